// Round 1
// baseline (74380.530 us; speedup 1.0000x reference)
//
#include <hip/hip_runtime.h>
#include <math.h>

#define B_    32
#define T_    2000
#define FIN_  80
#define H_    512
#define ROWS_ (B_ * T_)                 // 64000
#define BTH_  ((size_t)ROWS_ * H_)      // 32,768,000 floats
#define BH_   (B_ * H_)                 // 16384 floats

// ---------------------------------------------------------------------------
// P1: proj = x @ W_proj + b ; LayerNorm(g1,b1) ; exact GELU.
// Output layout [t*32+b][512] (the scan's [T,B,H]).
// 256 threads, 16 rows/block; thread owns cols j and j+256.
// ---------------------------------------------------------------------------
__global__ __launch_bounds__(256) void proj_ln_gelu(
    const float* __restrict__ x, const float* __restrict__ Wp,
    const float* __restrict__ bp, const float* __restrict__ g1,
    const float* __restrict__ be1, float* __restrict__ out)
{
  __shared__ float xs[16][84];   // 16 x-rows of 80 (pad 84)
  __shared__ float pr[16][512];  // pre-LN projection rows
  __shared__ float mv[16][2];    // mean, rstd per row
  const int tid = threadIdx.x;
  const int r0 = blockIdx.x * 16;

  for (int f = tid; f < 320; f += 256) {   // 16 rows * 20 float4
    int rr = f / 20, c4 = (f % 20) * 4;
    int r = r0 + rr; int b = r & 31; int t = r >> 5;
    float4 v = *(const float4*)(x + ((size_t)(b * T_ + t)) * FIN_ + c4);
    xs[rr][c4+0] = v.x; xs[rr][c4+1] = v.y; xs[rr][c4+2] = v.z; xs[rr][c4+3] = v.w;
  }
  __syncthreads();

  const int j = tid;
  float acc0[16], acc1[16];
#pragma unroll
  for (int rr = 0; rr < 16; ++rr) { acc0[rr] = 0.f; acc1[rr] = 0.f; }

  for (int k4 = 0; k4 < 20; ++k4) {
    float w0[4], w1[4];
#pragma unroll
    for (int i = 0; i < 4; ++i) {
      w0[i] = Wp[(k4*4+i)*H_ + j];
      w1[i] = Wp[(k4*4+i)*H_ + j + 256];
    }
#pragma unroll
    for (int rr = 0; rr < 16; ++rr) {
      float4 xv = *(const float4*)&xs[rr][k4*4];   // broadcast read
      acc0[rr] += xv.x*w0[0] + xv.y*w0[1] + xv.z*w0[2] + xv.w*w0[3];
      acc1[rr] += xv.x*w1[0] + xv.y*w1[1] + xv.z*w1[2] + xv.w*w1[3];
    }
  }

  const float bj0 = bp[j], bj1 = bp[j+256];
#pragma unroll
  for (int rr = 0; rr < 16; ++rr) {
    pr[rr][j]     = acc0[rr] + bj0;
    pr[rr][j+256] = acc1[rr] + bj1;
  }
  __syncthreads();

  // LN stats: 4 waves, wave w reduces rows 4w..4w+3
  const int wv = tid >> 6, ln = tid & 63;
  for (int rr = wv*4; rr < wv*4+4; ++rr) {
    float s = 0.f, ss = 0.f;
#pragma unroll
    for (int q = 0; q < 8; ++q) { float v = pr[rr][ln + q*64]; s += v; ss += v*v; }
#pragma unroll
    for (int o = 32; o > 0; o >>= 1) { s += __shfl_xor(s, o, 64); ss += __shfl_xor(ss, o, 64); }
    if (ln == 0) {
      float m = s * (1.f/512.f);
      float var = ss * (1.f/512.f) - m*m;
      mv[rr][0] = m; mv[rr][1] = 1.f / sqrtf(var + 1e-5f);
    }
  }
  __syncthreads();

  const float ga0 = g1[j], ga1 = g1[j+256], bo0 = be1[j], bo1 = be1[j+256];
#pragma unroll
  for (int rr = 0; rr < 16; ++rr) {
    float m = mv[rr][0], rs = mv[rr][1];
    float v0 = (pr[rr][j]     - m) * rs * ga0 + bo0;
    float v1 = (pr[rr][j+256] - m) * rs * ga1 + bo1;
    v0 = v0 * 0.5f * (1.f + erff(v0 * 0.70710678118654752f));
    v1 = v1 * 0.5f * (1.f + erff(v1 * 0.70710678118654752f));
    size_t ro = (size_t)(r0 + rr) * H_;
    out[ro + j] = v0; out[ro + j + 256] = v1;
  }
}

// ---------------------------------------------------------------------------
// P2/P4: C[64000,512] = A[64000,512] @ Bm[512,512] + bias, fp32.
// 128x128 tile, BK=16, 256 threads, 8x8 micro-tile, reg-prefetch pipeline.
// ---------------------------------------------------------------------------
__global__ __launch_bounds__(256) void gemm512(
    const float* __restrict__ A, const float* __restrict__ Bm,
    const float* __restrict__ bias, float* __restrict__ C)
{
  __shared__ float As[16][132];   // transposed A tile, pad 132
  __shared__ float Bs[16][132];
  const int tid = threadIdx.x;
  const int n0 = blockIdx.x * 128;
  const int m0 = blockIdx.y * 128;
  const int tx = tid & 15, ty = tid >> 4;

  float acc[8][8];
#pragma unroll
  for (int i = 0; i < 8; ++i)
#pragma unroll
    for (int jj = 0; jj < 8; ++jj) acc[i][jj] = 0.f;

  float4 pa[2], pb[2];
#pragma unroll
  for (int i = 0; i < 2; ++i) {
    int f = i*256 + tid;
    int mm = f >> 2, kk4 = (f & 3) * 4;
    pa[i] = *(const float4*)(A + (size_t)(m0+mm)*H_ + kk4);
    int kk = f >> 5, nn4 = (f & 31) * 4;
    pb[i] = *(const float4*)(Bm + (size_t)kk*H_ + n0 + nn4);
  }

  for (int kt = 0; kt < 32; ++kt) {
    __syncthreads();
#pragma unroll
    for (int i = 0; i < 2; ++i) {
      int f = i*256 + tid;
      int mm = f >> 2, kk4 = (f & 3) * 4;
      As[kk4+0][mm] = pa[i].x; As[kk4+1][mm] = pa[i].y;
      As[kk4+2][mm] = pa[i].z; As[kk4+3][mm] = pa[i].w;
      int kk = f >> 5, nn4 = (f & 31) * 4;
      *(float4*)&Bs[kk][nn4] = pb[i];
    }
    __syncthreads();
    if (kt < 31) {
#pragma unroll
      for (int i = 0; i < 2; ++i) {
        int f = i*256 + tid;
        int mm = f >> 2, kk4 = (f & 3) * 4;
        pa[i] = *(const float4*)(A + (size_t)(m0+mm)*H_ + (kt+1)*16 + kk4);
        int kk = f >> 5, nn4 = (f & 31) * 4;
        pb[i] = *(const float4*)(Bm + (size_t)((kt+1)*16+kk)*H_ + n0 + nn4);
      }
    }
#pragma unroll
    for (int k = 0; k < 16; ++k) {
      float a[8], bb[8];
      *(float4*)(a+0) = *(const float4*)&As[k][ty*4];
      *(float4*)(a+4) = *(const float4*)&As[k][ty*4 + 64];
      *(float4*)(bb+0) = *(const float4*)&Bs[k][tx*4];
      *(float4*)(bb+4) = *(const float4*)&Bs[k][tx*4 + 64];
#pragma unroll
      for (int i = 0; i < 8; ++i)
#pragma unroll
        for (int jj = 0; jj < 8; ++jj) acc[i][jj] += a[i] * bb[jj];
    }
  }

  float4 bi0 = *(const float4*)(bias + n0 + tx*4);
  float4 bi1 = *(const float4*)(bias + n0 + tx*4 + 64);
#pragma unroll
  for (int i = 0; i < 8; ++i) {
    int m = m0 + ty*4 + (i & 3) + (i >> 2) * 64;
    float4 v0 = make_float4(acc[i][0]+bi0.x, acc[i][1]+bi0.y, acc[i][2]+bi0.z, acc[i][3]+bi0.w);
    float4 v1 = make_float4(acc[i][4]+bi1.x, acc[i][5]+bi1.y, acc[i][6]+bi1.z, acc[i][7]+bi1.w);
    *(float4*)(C + (size_t)m*H_ + n0 + tx*4)      = v0;
    *(float4*)(C + (size_t)m*H_ + n0 + tx*4 + 64) = v1;
  }
}

// ---------------------------------------------------------------------------
// P3/P5: LTC scan. 256 WGs = 32 batches x 8 column-slices (64 cols each).
// W_rec slice lives in REGISTERS (64 fp32/thread). h double-buffered in
// global; per-batch flag counter with agent-scope release/acquire.
// 512 threads: cq = tid&15 (col quad), kg = tid>>4 (16-k group).
// ---------------------------------------------------------------------------
__global__ __launch_bounds__(512) void ltc_scan(
    const float* __restrict__ Wrec,   // [512][512] layer slice
    const float* __restrict__ traw,   // [512] tau_raw layer slice
    float* __restrict__ xzys,         // [T][B][512] in: xz, out: ys (in-place)
    float* __restrict__ hbuf,         // [2][B][512] ping-pong h
    int* __restrict__ ctr,            // [B][16] flag counters (padded)
    float* __restrict__ hid)          // [B][512] final hidden out
{
  __shared__ float hl[512];
  __shared__ float pt[32 * 64];
  __shared__ float taus[64];

  const int tid = threadIdx.x;
  const int b  = blockIdx.x & 31;
  const int s  = blockIdx.x >> 5;
  const int j0 = s * 64;
  const int cq = tid & 15;
  const int kg = tid >> 4;

  // W_rec[:, j0 + cq*4 .. +3] for k = kg*16..kg*16+15  ->  registers
  float wreg[64];
#pragma unroll
  for (int kk = 0; kk < 16; ++kk) {
    float4 wv = *(const float4*)(Wrec + (size_t)(kg*16 + kk)*H_ + j0 + cq*4);
    wreg[kk*4+0] = wv.x; wreg[kk*4+1] = wv.y; wreg[kk*4+2] = wv.z; wreg[kk*4+3] = wv.w;
  }
  if (tid < 64) {
    float tr = traw[j0 + tid];
    taus[tid] = (tr > 20.f ? tr : log1pf(expf(tr))) + 0.1f;  // softplus + 0.1
  }
  int* cb = ctr + b * 16;
  __syncthreads();

  for (int t = 0; t < T_; ++t) {
    if (t > 0) {
      if (tid == 0) {
        const int want = 8 * t;
        while (__hip_atomic_load(cb, __ATOMIC_RELAXED, __HIP_MEMORY_SCOPE_AGENT) < want) {
          __builtin_amdgcn_s_sleep(1);
        }
      }
      __syncthreads();
      __builtin_amdgcn_fence(__ATOMIC_ACQUIRE, "agent");
      const float* hrd = hbuf + (size_t)(((t - 1) & 1)) * BH_;
      if (tid < 128) *(float4*)(hl + tid*4) = *(const float4*)(hrd + b*H_ + tid*4);
    } else {
      if (tid < 128) *(float4*)(hl + tid*4) = make_float4(0.f, 0.f, 0.f, 0.f);
    }
    __syncthreads();

    float xzv = 0.f;
    if (tid < 64) xzv = xzys[((size_t)t * B_ + b) * H_ + j0 + tid];

    float hr[16];
#pragma unroll
    for (int q = 0; q < 4; ++q)
      *(float4*)(hr + q*4) = *(const float4*)(hl + kg*16 + q*4);

    float a0 = 0.f, a1 = 0.f, a2 = 0.f, a3 = 0.f;
#pragma unroll
    for (int kk = 0; kk < 16; ++kk) {
      float h = hr[kk];
      a0 += h * wreg[kk*4+0]; a1 += h * wreg[kk*4+1];
      a2 += h * wreg[kk*4+2]; a3 += h * wreg[kk*4+3];
    }
    *(float4*)(pt + kg*64 + cq*4) = make_float4(a0, a1, a2, a3);
    __syncthreads();

    if (tid < 64) {
      float ssum = 0.f;
#pragma unroll
      for (int g = 0; g < 32; ++g) ssum += pt[g*64 + tid];
      float z = xzv + ssum;
      float th = tanhf(z);
      float hold = hl[j0 + tid];
      float hn = hold + (th - hold) / taus[tid];
      xzys[((size_t)t * B_ + b) * H_ + j0 + tid] = hn;          // ys (in-place)
      (hbuf + (size_t)(t & 1) * BH_)[b*H_ + j0 + tid] = hn;     // h for step t
      if (t == T_ - 1) hid[b*H_ + j0 + tid] = hn;
    }
    __syncthreads();
    if (tid == 0)
      __hip_atomic_fetch_add(cb, 1, __ATOMIC_RELEASE, __HIP_MEMORY_SCOPE_AGENT);
  }
}

// ---------------------------------------------------------------------------
// P6: encoded = LN(ys1) with lno_g/lno_b ; [t*32+b] rows -> [b][t] output.
// ---------------------------------------------------------------------------
__global__ __launch_bounds__(256) void ln_out(
    const float* __restrict__ in, const float* __restrict__ g,
    const float* __restrict__ be, float* __restrict__ out)
{
  __shared__ float red[8];
  __shared__ float mv2[2];
  const int r = blockIdx.x;            // input row = t*32 + b
  const int t = r >> 5, b = r & 31;
  const int tid = threadIdx.x;

  const float2 v = *(const float2*)(in + (size_t)r * H_ + tid*2);
  float s = v.x + v.y, ss = v.x*v.x + v.y*v.y;
#pragma unroll
  for (int o = 32; o > 0; o >>= 1) { s += __shfl_xor(s, o, 64); ss += __shfl_xor(ss, o, 64); }
  const int wv = tid >> 6;
  if ((tid & 63) == 0) { red[wv] = s; red[4 + wv] = ss; }
  __syncthreads();
  if (tid == 0) {
    float S  = red[0] + red[1] + red[2] + red[3];
    float SS = red[4] + red[5] + red[6] + red[7];
    float m = S * (1.f/512.f);
    mv2[0] = m;
    mv2[1] = 1.f / sqrtf(SS * (1.f/512.f) - m*m + 1e-5f);
  }
  __syncthreads();
  const float m = mv2[0], rs = mv2[1];
  const float2 gg = *(const float2*)(g + tid*2);
  const float2 bb = *(const float2*)(be + tid*2);
  float2 o2;
  o2.x = (v.x - m) * rs * gg.x + bb.x;
  o2.y = (v.y - m) * rs * gg.y + bb.y;
  *(float2*)(out + ((size_t)b * T_ + t) * H_ + tid*2) = o2;
}

// ---------------------------------------------------------------------------
extern "C" void kernel_launch(void* const* d_in, const int* in_sizes, int n_in,
                              void* d_out, int out_size, void* d_ws, size_t ws_size,
                              hipStream_t stream)
{
  (void)in_sizes; (void)n_in; (void)out_size; (void)ws_size;
  const float* x   = (const float*)d_in[0];
  const float* Wp  = (const float*)d_in[1];
  const float* bp  = (const float*)d_in[2];
  const float* g1  = (const float*)d_in[3];
  const float* be1 = (const float*)d_in[4];
  const float* Win = (const float*)d_in[5];   // [2][512][512]
  const float* Wrc = (const float*)d_in[6];   // [2][512][512]
  const float* brn = (const float*)d_in[7];   // [2][512]
  const float* tra = (const float*)d_in[8];   // [2][512]
  const float* gno = (const float*)d_in[9];
  const float* bno = (const float*)d_in[10];
  float* outp = (float*)d_out;

  char* ws = (char*)d_ws;
  int*   ctr  = (int*)ws;                          // 32*16 ints = 2 KB
  float* hbuf = (float*)(ws + 4096);               // 2*BH_ floats = 128 KB
  float* bufA = (float*)(ws + 4096 + 2 * BH_ * sizeof(float));  // 131 MB

  // P1: x -> proj -> LN -> GELU, into bufA ([T,B,H] rows)
  proj_ln_gelu<<<dim3(ROWS_/16), 256, 0, stream>>>(x, Wp, bp, g1, be1, bufA);

  // P2: xz0 = bufA @ W_in[0] + b_rnn[0]  -> d_out scratch region
  gemm512<<<dim3(4, ROWS_/128), 256, 0, stream>>>(bufA, Win, brn, outp);

  // P3: layer-0 scan (in-place over d_out region); hidden[0] -> d_out tail
  hipMemsetAsync(ctr, 0, 32 * 16 * sizeof(int), stream);
  ltc_scan<<<256, 512, 0, stream>>>(Wrc, tra, outp, hbuf, ctr, outp + BTH_);

  // P4: xz1 = ys0 @ W_in[1] + b_rnn[1] -> bufA
  gemm512<<<dim3(4, ROWS_/128), 256, 0, stream>>>(outp, Win + H_*H_, brn + H_, bufA);

  // P5: layer-1 scan (in-place over bufA); hidden[1] -> d_out tail
  hipMemsetAsync(ctr, 0, 32 * 16 * sizeof(int), stream);
  ltc_scan<<<256, 512, 0, stream>>>(Wrc + H_*H_, tra + H_, bufA, hbuf, ctr,
                                    outp + BTH_ + BH_);

  // P6: encoded = LN(ys1), [t,b] -> [b,t], into d_out
  ln_out<<<ROWS_, 256, 0, stream>>>(bufA, gno, bno, outp);
}

// Round 2
// 10001.585 us; speedup vs baseline: 7.4369x; 7.4369x over previous
//
#include <hip/hip_runtime.h>
#include <math.h>

#define B_    32
#define T_    2000
#define FIN_  80
#define H_    512
#define ROWS_ (B_ * T_)                 // 64000
#define BTH_  ((size_t)ROWS_ * H_)      // 32,768,000 floats
#define BH_   (B_ * H_)                 // 16384 floats

typedef unsigned long long u64;

// ---------------------------------------------------------------------------
// P1: proj = x @ W_proj + b ; LayerNorm(g1,b1) ; exact GELU.
// Output layout [t*32+b][512] (the scan's [T,B,H]).
// ---------------------------------------------------------------------------
__global__ __launch_bounds__(256) void proj_ln_gelu(
    const float* __restrict__ x, const float* __restrict__ Wp,
    const float* __restrict__ bp, const float* __restrict__ g1,
    const float* __restrict__ be1, float* __restrict__ out)
{
  __shared__ float xs[16][84];   // 16 x-rows of 80 (pad 84)
  __shared__ float pr[16][512];  // pre-LN projection rows
  __shared__ float mv[16][2];    // mean, rstd per row
  const int tid = threadIdx.x;
  const int r0 = blockIdx.x * 16;

  for (int f = tid; f < 320; f += 256) {   // 16 rows * 20 float4
    int rr = f / 20, c4 = (f % 20) * 4;
    int r = r0 + rr; int b = r & 31; int t = r >> 5;
    float4 v = *(const float4*)(x + ((size_t)(b * T_ + t)) * FIN_ + c4);
    xs[rr][c4+0] = v.x; xs[rr][c4+1] = v.y; xs[rr][c4+2] = v.z; xs[rr][c4+3] = v.w;
  }
  __syncthreads();

  const int j = tid;
  float acc0[16], acc1[16];
#pragma unroll
  for (int rr = 0; rr < 16; ++rr) { acc0[rr] = 0.f; acc1[rr] = 0.f; }

  for (int k4 = 0; k4 < 20; ++k4) {
    float w0[4], w1[4];
#pragma unroll
    for (int i = 0; i < 4; ++i) {
      w0[i] = Wp[(k4*4+i)*H_ + j];
      w1[i] = Wp[(k4*4+i)*H_ + j + 256];
    }
#pragma unroll
    for (int rr = 0; rr < 16; ++rr) {
      float4 xv = *(const float4*)&xs[rr][k4*4];   // broadcast read
      acc0[rr] += xv.x*w0[0] + xv.y*w0[1] + xv.z*w0[2] + xv.w*w0[3];
      acc1[rr] += xv.x*w1[0] + xv.y*w1[1] + xv.z*w1[2] + xv.w*w1[3];
    }
  }

  const float bj0 = bp[j], bj1 = bp[j+256];
#pragma unroll
  for (int rr = 0; rr < 16; ++rr) {
    pr[rr][j]     = acc0[rr] + bj0;
    pr[rr][j+256] = acc1[rr] + bj1;
  }
  __syncthreads();

  const int wv = tid >> 6, ln = tid & 63;
  for (int rr = wv*4; rr < wv*4+4; ++rr) {
    float s = 0.f, ss = 0.f;
#pragma unroll
    for (int q = 0; q < 8; ++q) { float v = pr[rr][ln + q*64]; s += v; ss += v*v; }
#pragma unroll
    for (int o = 32; o > 0; o >>= 1) { s += __shfl_xor(s, o, 64); ss += __shfl_xor(ss, o, 64); }
    if (ln == 0) {
      float m = s * (1.f/512.f);
      float var = ss * (1.f/512.f) - m*m;
      mv[rr][0] = m; mv[rr][1] = 1.f / sqrtf(var + 1e-5f);
    }
  }
  __syncthreads();

  const float ga0 = g1[j], ga1 = g1[j+256], bo0 = be1[j], bo1 = be1[j+256];
#pragma unroll
  for (int rr = 0; rr < 16; ++rr) {
    float m = mv[rr][0], rs = mv[rr][1];
    float v0 = (pr[rr][j]     - m) * rs * ga0 + bo0;
    float v1 = (pr[rr][j+256] - m) * rs * ga1 + bo1;
    v0 = v0 * 0.5f * (1.f + erff(v0 * 0.70710678118654752f));
    v1 = v1 * 0.5f * (1.f + erff(v1 * 0.70710678118654752f));
    size_t ro = (size_t)(r0 + rr) * H_;
    out[ro + j] = v0; out[ro + j + 256] = v1;
  }
}

// ---------------------------------------------------------------------------
// P2/P4: C[64000,512] = A[64000,512] @ Bm[512,512] + bias, fp32.
// 128x128 tile, BK=16, 256 threads, 8x8 micro-tile, reg-prefetch pipeline.
// ---------------------------------------------------------------------------
__global__ __launch_bounds__(256) void gemm512(
    const float* __restrict__ A, const float* __restrict__ Bm,
    const float* __restrict__ bias, float* __restrict__ C)
{
  __shared__ float As[16][132];
  __shared__ float Bs[16][132];
  const int tid = threadIdx.x;
  const int n0 = blockIdx.x * 128;
  const int m0 = blockIdx.y * 128;
  const int tx = tid & 15, ty = tid >> 4;

  float acc[8][8];
#pragma unroll
  for (int i = 0; i < 8; ++i)
#pragma unroll
    for (int jj = 0; jj < 8; ++jj) acc[i][jj] = 0.f;

  float4 pa[2], pb[2];
#pragma unroll
  for (int i = 0; i < 2; ++i) {
    int f = i*256 + tid;
    int mm = f >> 2, kk4 = (f & 3) * 4;
    pa[i] = *(const float4*)(A + (size_t)(m0+mm)*H_ + kk4);
    int kk = f >> 5, nn4 = (f & 31) * 4;
    pb[i] = *(const float4*)(Bm + (size_t)kk*H_ + n0 + nn4);
  }

  for (int kt = 0; kt < 32; ++kt) {
    __syncthreads();
#pragma unroll
    for (int i = 0; i < 2; ++i) {
      int f = i*256 + tid;
      int mm = f >> 2, kk4 = (f & 3) * 4;
      As[kk4+0][mm] = pa[i].x; As[kk4+1][mm] = pa[i].y;
      As[kk4+2][mm] = pa[i].z; As[kk4+3][mm] = pa[i].w;
      int kk = f >> 5, nn4 = (f & 31) * 4;
      *(float4*)&Bs[kk][nn4] = pb[i];
    }
    __syncthreads();
    if (kt < 31) {
#pragma unroll
      for (int i = 0; i < 2; ++i) {
        int f = i*256 + tid;
        int mm = f >> 2, kk4 = (f & 3) * 4;
        pa[i] = *(const float4*)(A + (size_t)(m0+mm)*H_ + (kt+1)*16 + kk4);
        int kk = f >> 5, nn4 = (f & 31) * 4;
        pb[i] = *(const float4*)(Bm + (size_t)((kt+1)*16+kk)*H_ + n0 + nn4);
      }
    }
#pragma unroll
    for (int k = 0; k < 16; ++k) {
      float a[8], bb[8];
      *(float4*)(a+0) = *(const float4*)&As[k][ty*4];
      *(float4*)(a+4) = *(const float4*)&As[k][ty*4 + 64];
      *(float4*)(bb+0) = *(const float4*)&Bs[k][tx*4];
      *(float4*)(bb+4) = *(const float4*)&Bs[k][tx*4 + 64];
#pragma unroll
      for (int i = 0; i < 8; ++i)
#pragma unroll
        for (int jj = 0; jj < 8; ++jj) acc[i][jj] += a[i] * bb[jj];
    }
  }

  float4 bi0 = *(const float4*)(bias + n0 + tx*4);
  float4 bi1 = *(const float4*)(bias + n0 + tx*4 + 64);
#pragma unroll
  for (int i = 0; i < 8; ++i) {
    int m = m0 + ty*4 + (i & 3) + (i >> 2) * 64;
    float4 v0 = make_float4(acc[i][0]+bi0.x, acc[i][1]+bi0.y, acc[i][2]+bi0.z, acc[i][3]+bi0.w);
    float4 v1 = make_float4(acc[i][4]+bi1.x, acc[i][5]+bi1.y, acc[i][6]+bi1.z, acc[i][7]+bi1.w);
    *(float4*)(C + (size_t)m*H_ + n0 + tx*4)      = v0;
    *(float4*)(C + (size_t)m*H_ + n0 + tx*4 + 64) = v1;
  }
}

// ---------------------------------------------------------------------------
// P3/P5: LTC scan. 256 WGs = 32 batches x 8 column-slices (64 cols each).
// W_rec slice in REGISTERS (64 fp32/thread). Cross-WG h exchange via
// point-coherent (sc0 sc1, IF$-level) relaxed atomics — NO cache-wide
// fences (the previous version's agent acquire/release fences cost ~16 us
// per step in full L2 invalidate/writeback).
// Ordering: h-stores (wave 0) -> s_waitcnt vmcnt(0) (wave 0) -> flag++.
// Consumer: spin relaxed flag -> barrier -> L2-bypass atomic loads of h.
// h double-buffered in hbuf (ping-pong), safe as before.
// ---------------------------------------------------------------------------
__global__ __launch_bounds__(512) void ltc_scan(
    const float* __restrict__ Wrec,   // [512][512] layer slice
    const float* __restrict__ traw,   // [512] tau_raw layer slice
    float* __restrict__ xzys,         // [T][B][512] in: xz, out: ys (in-place)
    u64* __restrict__ hbuf,           // [2][B][256] ping-pong h (as float2)
    int* __restrict__ ctr,            // [B][16] flag counters (padded)
    float* __restrict__ hid)          // [B][512] final hidden out
{
  __shared__ float hl[512];
  __shared__ float pt[32 * 64];
  __shared__ float taus[64];

  const int tid = threadIdx.x;
  const int b  = blockIdx.x & 31;
  const int s  = blockIdx.x >> 5;
  const int j0 = s * 64;
  const int cq = tid & 15;
  const int kg = tid >> 4;

  // W_rec[:, j0 + cq*4 .. +3] for k = kg*16..kg*16+15  ->  registers
  float wreg[64];
#pragma unroll
  for (int kk = 0; kk < 16; ++kk) {
    float4 wv = *(const float4*)(Wrec + (size_t)(kg*16 + kk)*H_ + j0 + cq*4);
    wreg[kk*4+0] = wv.x; wreg[kk*4+1] = wv.y; wreg[kk*4+2] = wv.z; wreg[kk*4+3] = wv.w;
  }
  if (tid < 64) {
    float tr = traw[j0 + tid];
    taus[tid] = (tr > 20.f ? tr : log1pf(expf(tr))) + 0.1f;  // softplus + 0.1
  }
  int* cb = ctr + b * 16;
  __syncthreads();

  for (int t = 0; t < T_; ++t) {
    // ---- A: obtain h(t-1) into hl ----
    if (t > 0) {
      if (tid == 0) {
        const int want = 8 * t;
        while (__hip_atomic_load(cb, __ATOMIC_RELAXED, __HIP_MEMORY_SCOPE_AGENT) < want) {
          __builtin_amdgcn_s_sleep(1);
        }
      }
      __syncthreads();   // B1: flag observed by all waves
      const u64* hrd = hbuf + (size_t)((t - 1) & 1) * (B_ * 256) + b * 256;
      if (tid < 256) {
        u64 v = __hip_atomic_load(hrd + tid, __ATOMIC_RELAXED, __HIP_MEMORY_SCOPE_AGENT);
        union { u64 u; float f[2]; } cv; cv.u = v;
        hl[tid*2]   = cv.f[0];
        hl[tid*2+1] = cv.f[1];
      }
    } else {
      if (tid < 128) *(float4*)(hl + tid*4) = make_float4(0.f, 0.f, 0.f, 0.f);
    }
    // xz prefetch (wave 0 only; wave 0 is also the only writer of xzys[t],
    // so the in-place overwrite is ordered by the compiler's use-waitcnt)
    float2 xzv = make_float2(0.f, 0.f);
    if (tid < 32)
      xzv = *(const float2*)(xzys + ((size_t)t * B_ + b) * H_ + j0 + tid*2);
    __syncthreads();   // B2: hl ready

    // ---- B: matvec partials ----
    float hr[16];
#pragma unroll
    for (int q = 0; q < 4; ++q)
      *(float4*)(hr + q*4) = *(const float4*)(hl + kg*16 + q*4);

    float a0 = 0.f, a1 = 0.f, a2 = 0.f, a3 = 0.f;
#pragma unroll
    for (int kk = 0; kk < 16; ++kk) {
      float h = hr[kk];
      a0 += h * wreg[kk*4+0]; a1 += h * wreg[kk*4+1];
      a2 += h * wreg[kk*4+2]; a3 += h * wreg[kk*4+3];
    }
    *(float4*)(pt + kg*64 + cq*4) = make_float4(a0, a1, a2, a3);
    __syncthreads();   // B3: partials ready

    // ---- C: reduce + update + publish (wave 0, 2 cols/thread) ----
    if (tid < 32) {
      float s0 = 0.f, s1 = 0.f;
#pragma unroll
      for (int g = 0; g < 32; ++g) {
        float2 p = *(const float2*)(pt + g*64 + tid*2);
        s0 += p.x; s1 += p.y;
      }
      float z0 = xzv.x + s0, z1 = xzv.y + s1;
      float th0 = tanhf(z0), th1 = tanhf(z1);
      float h0 = hl[j0 + tid*2], h1 = hl[j0 + tid*2 + 1];
      float hn0 = h0 + (th0 - h0) / taus[tid*2];
      float hn1 = h1 + (th1 - h1) / taus[tid*2 + 1];
      *(float2*)(xzys + ((size_t)t * B_ + b) * H_ + j0 + tid*2) = make_float2(hn0, hn1);
      union { u64 u; float f[2]; } cv; cv.f[0] = hn0; cv.f[1] = hn1;
      u64* hw = hbuf + (size_t)(t & 1) * (B_ * 256) + b * 256 + s * 32 + tid;
      __hip_atomic_store(hw, cv.u, __ATOMIC_RELAXED, __HIP_MEMORY_SCOPE_AGENT);
      if (t == T_ - 1)
        *(float2*)(hid + b*H_ + j0 + tid*2) = make_float2(hn0, hn1);
    }
    if (tid == 0) {
      // h publishes were issued by wave 0; drain them to the coherent point,
      // THEN raise the flag. No cache-wide maintenance.
      asm volatile("s_waitcnt vmcnt(0)" ::: "memory");
      __hip_atomic_fetch_add(cb, 1, __ATOMIC_RELAXED, __HIP_MEMORY_SCOPE_AGENT);
    }
    // no trailing barrier needed: next iteration's hl overwrite is gated by
    // B1 (flag) / B2, and pt overwrite by B2.
  }
}

// ---------------------------------------------------------------------------
// P6: encoded = LN(ys1) with lno_g/lno_b ; [t*32+b] rows -> [b][t] output.
// ---------------------------------------------------------------------------
__global__ __launch_bounds__(256) void ln_out(
    const float* __restrict__ in, const float* __restrict__ g,
    const float* __restrict__ be, float* __restrict__ out)
{
  __shared__ float red[8];
  __shared__ float mv2[2];
  const int r = blockIdx.x;            // input row = t*32 + b
  const int t = r >> 5, b = r & 31;
  const int tid = threadIdx.x;

  const float2 v = *(const float2*)(in + (size_t)r * H_ + tid*2);
  float s = v.x + v.y, ss = v.x*v.x + v.y*v.y;
#pragma unroll
  for (int o = 32; o > 0; o >>= 1) { s += __shfl_xor(s, o, 64); ss += __shfl_xor(ss, o, 64); }
  const int wv = tid >> 6;
  if ((tid & 63) == 0) { red[wv] = s; red[4 + wv] = ss; }
  __syncthreads();
  if (tid == 0) {
    float S  = red[0] + red[1] + red[2] + red[3];
    float SS = red[4] + red[5] + red[6] + red[7];
    float m = S * (1.f/512.f);
    mv2[0] = m;
    mv2[1] = 1.f / sqrtf(SS * (1.f/512.f) - m*m + 1e-5f);
  }
  __syncthreads();
  const float m = mv2[0], rs = mv2[1];
  const float2 gg = *(const float2*)(g + tid*2);
  const float2 bb = *(const float2*)(be + tid*2);
  float2 o2;
  o2.x = (v.x - m) * rs * gg.x + bb.x;
  o2.y = (v.y - m) * rs * gg.y + bb.y;
  *(float2*)(out + ((size_t)b * T_ + t) * H_ + tid*2) = o2;
}

// ---------------------------------------------------------------------------
extern "C" void kernel_launch(void* const* d_in, const int* in_sizes, int n_in,
                              void* d_out, int out_size, void* d_ws, size_t ws_size,
                              hipStream_t stream)
{
  (void)in_sizes; (void)n_in; (void)out_size; (void)ws_size;
  const float* x   = (const float*)d_in[0];
  const float* Wp  = (const float*)d_in[1];
  const float* bp  = (const float*)d_in[2];
  const float* g1  = (const float*)d_in[3];
  const float* be1 = (const float*)d_in[4];
  const float* Win = (const float*)d_in[5];   // [2][512][512]
  const float* Wrc = (const float*)d_in[6];   // [2][512][512]
  const float* brn = (const float*)d_in[7];   // [2][512]
  const float* tra = (const float*)d_in[8];   // [2][512]
  const float* gno = (const float*)d_in[9];
  const float* bno = (const float*)d_in[10];
  float* outp = (float*)d_out;

  char* ws = (char*)d_ws;
  int*  ctr  = (int*)ws;                           // 32*16 ints = 2 KB
  u64*  hbuf = (u64*)(ws + 4096);                  // 2*32*256 u64 = 128 KB
  float* bufA = (float*)(ws + 4096 + 131072);      // 131 MB

  // P1: x -> proj -> LN -> GELU, into bufA ([T,B,H] rows)
  proj_ln_gelu<<<dim3(ROWS_/16), 256, 0, stream>>>(x, Wp, bp, g1, be1, bufA);

  // P2: xz0 = bufA @ W_in[0] + b_rnn[0]  -> d_out scratch region
  gemm512<<<dim3(4, ROWS_/128), 256, 0, stream>>>(bufA, Win, brn, outp);

  // P3: layer-0 scan (in-place over d_out region); hidden[0] -> d_out tail
  hipMemsetAsync(ctr, 0, 32 * 16 * sizeof(int), stream);
  ltc_scan<<<256, 512, 0, stream>>>(Wrc, tra, outp, hbuf, ctr, outp + BTH_);

  // P4: xz1 = ys0 @ W_in[1] + b_rnn[1] -> bufA
  gemm512<<<dim3(4, ROWS_/128), 256, 0, stream>>>(outp, Win + H_*H_, brn + H_, bufA);

  // P5: layer-1 scan (in-place over bufA); hidden[1] -> d_out tail
  hipMemsetAsync(ctr, 0, 32 * 16 * sizeof(int), stream);
  ltc_scan<<<256, 512, 0, stream>>>(Wrc + H_*H_, tra + H_, bufA, hbuf, ctr,
                                    outp + BTH_ + BH_);

  // P6: encoded = LN(ys1), [t,b] -> [b,t], into d_out
  ln_out<<<ROWS_, 256, 0, stream>>>(bufA, gno, bno, outp);
}